// Round 1
// baseline (74.670 us; speedup 1.0000x reference)
//
#include <hip/hip_runtime.h>

// Problem constants (from reference setup_inputs):
//   bs=4, v=8192, n=20, SUPPORT_NUM=4, KERNEL_NUM=32
#define BS 4
#define NV 8192
#define NN 20
#define SN 4
#define KN 32

// One thread per (b, vertex, k) output element.
// tid = (b*NV + vi)*KN + k. 32 k-lanes share one (b,vi): their 20 neighbor
// index loads are wave-broadcast (same address), the neighbor-vertex gather
// stays within a 96 KB per-batch vertex array (L1/L2 resident).
__global__ __launch_bounds__(256) void op3d_kernel(
    const int*   __restrict__ nbr,     // (BS, NV, NN)
    const float* __restrict__ verts,   // (BS, NV, 3)
    const float* __restrict__ wgt,     // (1,1,SN,KN) -> (SN,KN)
    const float* __restrict__ disp,    // (3, SN*KN)
    float*       __restrict__ out)     // (BS, NV, KN)
{
    const int tid = blockIdx.x * blockDim.x + threadIdx.x;
    const int k  = tid & (KN - 1);
    const int bv = tid >> 5;               // b*NV + vi
    const int b  = bv >> 13;               // NV = 8192 = 2^13

    // Per-thread displacement columns D[s][d] = disp[d][s*KN + k]
    float D0[SN], D1[SN], D2[SN];
#pragma unroll
    for (int s = 0; s < SN; ++s) {
        const int col = s * KN + k;
        D0[s] = disp[0 * SN * KN + col];
        D1[s] = disp[1 * SN * KN + col];
        D2[s] = disp[2 * SN * KN + col];
    }
    float w[SN];
#pragma unroll
    for (int s = 0; s < SN; ++s) w[s] = wgt[s * KN + k];

    // Own vertex
    const float vx = verts[(size_t)bv * 3 + 0];
    const float vy = verts[(size_t)bv * 3 + 1];
    const float vz = verts[(size_t)bv * 3 + 2];

    const int*   nb     = nbr + (size_t)bv * NN;
    const float* vbatch = verts + (size_t)b * NV * 3;

    // relu >= 0, so max over n of relu(theta) has floor 0
    float m[SN] = {0.f, 0.f, 0.f, 0.f};

#pragma unroll 4
    for (int j = 0; j < NN; ++j) {
        const int idx = nb[j];
        const float nx = vbatch[idx * 3 + 0];
        const float ny = vbatch[idx * 3 + 1];
        const float nz = vbatch[idx * 3 + 2];
        const float dx = nx - vx;
        const float dy = ny - vy;
        const float dz = nz - vz;
#pragma unroll
        for (int s = 0; s < SN; ++s) {
            float t = fmaf(dx, D0[s], fmaf(dy, D1[s], dz * D2[s]));
            t = fmaxf(t, 0.f);          // relu
            m[s] = fmaxf(m[s], t);      // running max over neighbors
        }
    }

    float acc = 0.f;
#pragma unroll
    for (int s = 0; s < SN; ++s) acc = fmaf(m[s], w[s], acc);

    out[tid] = acc;   // (b*NV + vi)*KN + k == tid : fully coalesced
}

extern "C" void kernel_launch(void* const* d_in, const int* in_sizes, int n_in,
                              void* d_out, int out_size, void* d_ws, size_t ws_size,
                              hipStream_t stream) {
    const int*   nbr   = (const int*)d_in[0];    // neighbor_index (4,8192,20)
    const float* verts = (const float*)d_in[1];  // vertices (4,8192,3)
    const float* wgt   = (const float*)d_in[2];  // weights (1,1,4,32)
    const float* disp  = (const float*)d_in[3];  // displacement (3,128)
    float* out = (float*)d_out;                  // (4,8192,32) = 1,048,576 floats

    const int total = BS * NV * KN;              // 1,048,576 threads
    const int block = 256;
    const int grid  = total / block;             // 4096 blocks
    op3d_kernel<<<grid, block, 0, stream>>>(nbr, verts, wgt, disp, out);
}

// Round 2
// 68.482 us; speedup vs baseline: 1.0904x; 1.0904x over previous
//
#include <hip/hip_runtime.h>

// Problem constants (from reference setup_inputs):
//   bs=4, v=8192, n=20, SUPPORT_NUM=4, KERNEL_NUM=32
#define BS 4
#define NV 8192
#define NN 20
#define SN 4
#define KN 32
#define GPB 8              // (b,v) groups per block
#define BLOCK (GPB * KN)   // 256 threads

// Two-phase kernel:
//  Phase 1: 160 threads cooperatively load the block's 8x20 neighbor indices
//           (coalesced), gather neighbor xyz ONCE, subtract own vertex, stage
//           (dx,dy,dz,0) in LDS.  Kills the 32x-redundant gather of the naive
//           one-thread-per-(b,v,k) layout.
//  Phase 2: thread (g,k) loops j=0..19: one ds_read_b128 (same-address
//           broadcast within the 32-lane k-group -> conflict-free) + 16 VALU
//           (mul+fma+fma+max3 per support).
__global__ __launch_bounds__(BLOCK) void op3d_kernel(
    const int*   __restrict__ nbr,     // (BS, NV, NN)
    const float* __restrict__ verts,   // (BS, NV, 3)
    const float* __restrict__ wgt,     // (1,1,SN,KN) -> (SN,KN)
    const float* __restrict__ disp,    // (3, SN*KN)
    float*       __restrict__ out)     // (BS, NV, KN)
{
    __shared__ float4 sdx[GPB * NN];   // (dx,dy,dz,0) per (group, j): 2560 B

    const int tx  = threadIdx.x;
    const int bv0 = blockIdx.x * GPB;

    // Per-thread constant loads (independent of LDS; issue before the sync
    // so their latency overlaps phase 1).
    const int k = tx & (KN - 1);
    float D0[SN], D1[SN], D2[SN], w[SN];
#pragma unroll
    for (int s = 0; s < SN; ++s) {
        const int col = s * KN + k;
        D0[s] = disp[0 * SN * KN + col];
        D1[s] = disp[1 * SN * KN + col];
        D2[s] = disp[2 * SN * KN + col];
        w[s]  = wgt[col];
    }

    // ---- Phase 1: cooperative gather ----
    if (tx < GPB * NN) {
        const int bv  = bv0 + tx / NN;       // this thread's (b,v)
        const int b   = bv >> 13;            // NV = 8192 = 2^13
        const int idx = nbr[bv0 * NN + tx];  // == nbr[bv*NN + j], coalesced
        const float* vb = verts + (size_t)b * NV * 3;
        const float nx = vb[idx * 3 + 0];
        const float ny = vb[idx * 3 + 1];
        const float nz = vb[idx * 3 + 2];
        const float vx = verts[(size_t)bv * 3 + 0];
        const float vy = verts[(size_t)bv * 3 + 1];
        const float vz = verts[(size_t)bv * 3 + 2];
        sdx[tx] = make_float4(nx - vx, ny - vy, nz - vz, 0.f);
    }
    __syncthreads();

    // ---- Phase 2: per-(g,k) reduction over neighbors ----
    const int g = tx >> 5;                   // group within block
    float m[SN] = {0.f, 0.f, 0.f, 0.f};     // relu floor
#pragma unroll 5
    for (int j = 0; j < NN; ++j) {
        const float4 d = sdx[g * NN + j];    // broadcast read
#pragma unroll
        for (int s = 0; s < SN; ++s) {
            float t = fmaf(d.x, D0[s], fmaf(d.y, D1[s], d.z * D2[s]));
            m[s] = fmaxf(m[s], fmaxf(t, 0.f));   // folds to v_max3_f32
        }
    }

    float acc = 0.f;
#pragma unroll
    for (int s = 0; s < SN; ++s) acc = fmaf(m[s], w[s], acc);

    out[(size_t)(bv0 + g) * KN + k] = acc;   // fully coalesced
}

extern "C" void kernel_launch(void* const* d_in, const int* in_sizes, int n_in,
                              void* d_out, int out_size, void* d_ws, size_t ws_size,
                              hipStream_t stream) {
    const int*   nbr   = (const int*)d_in[0];    // neighbor_index (4,8192,20)
    const float* verts = (const float*)d_in[1];  // vertices (4,8192,3)
    const float* wgt   = (const float*)d_in[2];  // weights (1,1,4,32)
    const float* disp  = (const float*)d_in[3];  // displacement (3,128)
    float* out = (float*)d_out;                  // (4,8192,32)

    const int grid = (BS * NV) / GPB;            // 4096 blocks
    op3d_kernel<<<grid, BLOCK, 0, stream>>>(nbr, verts, wgt, disp, out);
}

// Round 3
// 68.354 us; speedup vs baseline: 1.0924x; 1.0019x over previous
//
#include <hip/hip_runtime.h>

// Problem constants (from reference setup_inputs):
//   bs=4, v=8192, n=20, SUPPORT_NUM=4, KERNEL_NUM=32
#define BS 4
#define NV 8192
#define NN 20
#define SN 4
#define KN 32
#define GPB 8              // (b,v) groups per block
#define BLOCK (GPB * KN)   // 256 threads

// Two-phase kernel (R3: fully unrolled j-loop -> immediate-offset ds_read_b128,
// zero per-iteration address math; otherwise identical structure to R2).
//  Phase 1: 160 threads cooperatively load 8x20 neighbor indices (coalesced),
//           gather neighbor xyz once, subtract own vertex, stage float4 in LDS.
//  Phase 2: thread (g,k): 20 x [ds_read_b128 broadcast + 16 VALU
//           (mul+fma+fma+max3 per support)]. VALU floor: 320 insts/thread
//           = 640 cyc/wave ≈ 4.3 µs across the grid — the kernel's roofline.
__global__ __launch_bounds__(BLOCK) void op3d_kernel(
    const int*   __restrict__ nbr,     // (BS, NV, NN)
    const float* __restrict__ verts,   // (BS, NV, 3)
    const float* __restrict__ wgt,     // (1,1,SN,KN) -> (SN,KN)
    const float* __restrict__ disp,    // (3, SN*KN)
    float*       __restrict__ out)     // (BS, NV, KN)
{
    __shared__ float4 sdx[GPB * NN];   // 2560 B

    const int tx  = threadIdx.x;
    const int bv0 = blockIdx.x * GPB;

    // Per-thread constants (k-indexed, L1-resident; latency overlaps phase 1).
    const int k = tx & (KN - 1);
    float D0[SN], D1[SN], D2[SN], w[SN];
#pragma unroll
    for (int s = 0; s < SN; ++s) {
        const int col = s * KN + k;
        D0[s] = disp[0 * SN * KN + col];
        D1[s] = disp[1 * SN * KN + col];
        D2[s] = disp[2 * SN * KN + col];
        w[s]  = wgt[col];
    }

    // ---- Phase 1: cooperative gather ----
    if (tx < GPB * NN) {
        const int bv  = bv0 + tx / NN;       // magic-mul division by 20
        const int b   = bv >> 13;            // NV = 8192 = 2^13
        const int idx = nbr[bv0 * NN + tx];  // coalesced 160-int block
        const float* vb = verts + (size_t)b * NV * 3;
        const float nx = vb[idx * 3 + 0];
        const float ny = vb[idx * 3 + 1];
        const float nz = vb[idx * 3 + 2];
        const float vx = verts[(size_t)bv * 3 + 0];  // ~broadcast within wave
        const float vy = verts[(size_t)bv * 3 + 1];
        const float vz = verts[(size_t)bv * 3 + 2];
        sdx[tx] = make_float4(nx - vx, ny - vy, nz - vz, 0.f);
    }
    __syncthreads();

    // ---- Phase 2: per-(g,k) reduction over neighbors ----
    const int g = tx >> 5;
    const float4* sg = &sdx[g * NN];         // single base; j -> imm offset
    float m[SN] = {0.f, 0.f, 0.f, 0.f};     // relu floor
#pragma unroll
    for (int j = 0; j < NN; ++j) {           // FULL unroll: 20 imm-offset reads
        const float4 d = sg[j];
#pragma unroll
        for (int s = 0; s < SN; ++s) {
            float t = fmaf(d.x, D0[s], fmaf(d.y, D1[s], d.z * D2[s]));
            m[s] = fmaxf(m[s], fmaxf(t, 0.f));   // v_max3_f32
        }
    }

    float acc = 0.f;
#pragma unroll
    for (int s = 0; s < SN; ++s) acc = fmaf(m[s], w[s], acc);

    out[(size_t)(bv0 + g) * KN + k] = acc;   // fully coalesced
}

extern "C" void kernel_launch(void* const* d_in, const int* in_sizes, int n_in,
                              void* d_out, int out_size, void* d_ws, size_t ws_size,
                              hipStream_t stream) {
    const int*   nbr   = (const int*)d_in[0];    // neighbor_index (4,8192,20)
    const float* verts = (const float*)d_in[1];  // vertices (4,8192,3)
    const float* wgt   = (const float*)d_in[2];  // weights (1,1,4,32)
    const float* disp  = (const float*)d_in[3];  // displacement (3,128)
    float* out = (float*)d_out;                  // (4,8192,32)

    const int grid = (BS * NV) / GPB;            // 4096 blocks
    op3d_kernel<<<grid, BLOCK, 0, stream>>>(nbr, verts, wgt, disp, out);
}